// Round 6
// baseline (42.858 us; speedup 1.0000x reference)
//
#include <hip/hip_runtime.h>
#include <hip/hip_bf16.h>
#include <math.h>

#define HWV (1080 * 1920)
#define NPIX (2 * HWV)

typedef _Float16 half2 __attribute__((ext_vector_type(2)));
typedef __fp16   pk2   __attribute__((ext_vector_type(2)));
union U32H2 { unsigned u; half2 h; pk2 p; };

static __device__ inline float fdot2f(half2 a, half2 b, float c) {
    return __builtin_amdgcn_fdot2(a, b, c, false);
}

// ---------------------------------------------------------------------------
// Prep kernel: transpose grid (n,c,z,y,x) -> (n,y,x,z,c) and fold BN.
// ---------------------------------------------------------------------------
__global__ void prep_kernel(const float* __restrict__ grid,
                            const float* __restrict__ w1,
                            const float* __restrict__ b1,
                            const float* __restrict__ gamma,
                            const float* __restrict__ beta,
                            const float* __restrict__ mean,
                            const float* __restrict__ var,
                            const float* __restrict__ w2,
                            const float* __restrict__ b2,
                            float* __restrict__ wsg,   // 49152 floats
                            float* __restrict__ wsw) { // 81 floats
    int i = blockIdx.x * blockDim.x + threadIdx.x;
    if (i < 2 * 12 * 8 * 16 * 16) {
        int c = i % 12;
        int t = i / 12;
        int z = t % 8;  t /= 8;
        int x = t % 16; t /= 16;
        int y = t % 16;
        int n = t / 16;
        wsg[i] = grid[n * 24576 + c * 2048 + z * 256 + y * 16 + x];
    }
    if (i < 16) {
        float inv = gamma[i] / sqrtf(var[i] + 1e-5f);
        wsw[i]      = w1[i * 3 + 0] * inv;
        wsw[16 + i] = w1[i * 3 + 1] * inv;
        wsw[32 + i] = w1[i * 3 + 2] * inv;
        wsw[48 + i] = (b1[i] - mean[i]) * inv + beta[i];
        wsw[64 + i] = w2[i];
    }
    if (i == 0) wsw[80] = b2[0];
}

// ---------------------------------------------------------------------------
// Fused kernel. Block = 2 rows x 128 px. LDS slot (row, cell, z) holds the
// y-lerped grid values packed as (v[z], v[z+1]) half2 per channel. Per pixel:
// 6 ds_read_b128 + 24 v_dot2_f32_f16.
// ---------------------------------------------------------------------------
__global__ __launch_bounds__(256) void fused_kernel(
        const float* __restrict__ fullres,
        const float* __restrict__ wsg,
        const float* __restrict__ wsw,
        float* __restrict__ out) {
    __shared__ unsigned sg[2][3][8][12];   // [row][cell][z-slot][ch], half2

    const int tid = threadIdx.x;
    const int n   = blockIdx.z;
    const int ypair = blockIdx.y * 2;
    const int xs  = blockIdx.x * 128;

    const int a = (int)((float)xs * (15.0f / 1919.0f));
    const float* gbase = wsg + n * 24576;

    // ---- stage: 2 rows x 3 cells x 8 z-slots x 12 ch, y-lerped, z-paired ----
    for (int idx = tid; idx < 576; idx += 256) {
        int row = idx / 288;
        int rem = idx - row * 288;
        int k = rem / 96;
        int f = rem - k * 96;
        int z = f / 12;
        int c = f - z * 12;
        int z1 = min(z + 1, 7);
        int y = ypair + row;
        float gy = (float)y * (15.0f / 1079.0f);
        float y0f = floorf(gy);
        float ty = gy - y0f;
        int y0 = min((int)y0f, 15);
        int y1 = min(y0 + 1, 15);
        int xc = min(a + k, 15);
        const float* p0 = gbase + (y0 * 16 + xc) * 96;
        const float* p1 = gbase + (y1 * 16 + xc) * 96;
        float a0 = p0[z * 12 + c],  a1 = p1[z * 12 + c];
        float b0 = p0[z1 * 12 + c], b1 = p1[z1 * 12 + c];
        float v0 = fmaf(ty, a1 - a0, a0);
        float v1 = fmaf(ty, b1 - b0, b0);
        U32H2 t;
        t.p = __builtin_amdgcn_cvt_pkrtz(v0, v1);
        sg[row][k][z][c] = t.u;
    }
    __syncthreads();

    const int row = tid >> 7;          // wave-uniform
    const int lx  = tid & 127;
    const int x   = xs + lx;
    const int y   = ypair + row;
    const int p   = y * 1920 + x;

    const float* fr = fullres + n * 3 * HWV + p;
    float r = fr[0];
    float g = fr[HWV];
    float b = fr[2 * HWV];

    // ---- guide MLP (weights wave-uniform -> s_loads) ----
    float acc = wsw[80];
#pragma unroll
    for (int c = 0; c < 16; ++c) {
        float t = fmaf(wsw[c], r,
                  fmaf(wsw[16 + c], g,
                  fmaf(wsw[32 + c], b, wsw[48 + c])));
        t = fmaxf(t, 0.0f);
        acc = fmaf(wsw[64 + c], t, acc);
    }
    float e = __expf(-acc);
    float guide = __builtin_amdgcn_rcpf(1.0f + e);

    // ---- coords ----
    float gz = guide * 7.0f;
    float z0f = floorf(gz);
    float tz = gz - z0f;
    int z0 = min((int)z0f, 7);

    float gx = (float)x * (15.0f / 1919.0f);
    float x0f = floorf(gx);
    float tx = gx - x0f;
    int x0 = (int)x0f;
    int k0 = x0 - a;                   // 0..1
    int k1 = min(x0 + 1, 15) - a;      // 0..2

    float wx0 = 1.0f - tx, wx1 = tx;
    float wz0 = 1.0f - tz, wz1 = tz;

    U32H2 wp0u, wp1u;
    wp0u.p = __builtin_amdgcn_cvt_pkrtz(wx0 * wz0, wx0 * wz1);
    wp1u.p = __builtin_amdgcn_cvt_pkrtz(wx1 * wz0, wx1 * wz1);
    half2 wp0 = wp0u.h, wp1 = wp1u.h;

    const uint4* s0 = (const uint4*)&sg[row][k0][z0][0];
    const uint4* s1 = (const uint4*)&sg[row][k1][z0][0];
    uint4 q00 = s0[0], q01 = s0[1], q02 = s0[2];
    uint4 q10 = s1[0], q11 = s1[1], q12 = s1[2];

    unsigned u0[12] = {q00.x, q00.y, q00.z, q00.w, q01.x, q01.y, q01.z, q01.w,
                       q02.x, q02.y, q02.z, q02.w};
    unsigned u1[12] = {q10.x, q10.y, q10.z, q10.w, q11.x, q11.y, q11.z, q11.w,
                       q12.x, q12.y, q12.z, q12.w};

    float co[12];
#pragma unroll
    for (int c = 0; c < 12; ++c) {
        U32H2 h0, h1;
        h0.u = u0[c];
        h1.u = u1[c];
        co[c] = fdot2f(h1.h, wp1, fdot2f(h0.h, wp0, 0.0f));
    }

    // ---- apply coeffs ----
    float* op = out + n * 3 * HWV + p;
    op[0]       = fmaf(co[0], r, fmaf(co[1], g, fmaf(co[2],  b, co[3])));
    op[HWV]     = fmaf(co[4], r, fmaf(co[5], g, fmaf(co[6],  b, co[7])));
    op[2 * HWV] = fmaf(co[8], r, fmaf(co[9], g, fmaf(co[10], b, co[11])));
}

extern "C" void kernel_launch(void* const* d_in, const int* in_sizes, int n_in,
                              void* d_out, int out_size, void* d_ws, size_t ws_size,
                              hipStream_t stream) {
    const float* fullres = (const float*)d_in[0];
    const float* grid    = (const float*)d_in[1];
    const float* w1      = (const float*)d_in[2];
    const float* b1      = (const float*)d_in[3];
    const float* gamma   = (const float*)d_in[4];
    const float* beta    = (const float*)d_in[5];
    const float* mean    = (const float*)d_in[6];
    const float* var     = (const float*)d_in[7];
    const float* w2      = (const float*)d_in[8];
    const float* b2      = (const float*)d_in[9];
    float* out = (float*)d_out;

    float* wsg = (float*)d_ws;
    float* wsw = wsg + 49152;

    prep_kernel<<<192, 256, 0, stream>>>(grid, w1, b1, gamma, beta, mean, var,
                                         w2, b2, wsg, wsw);

    dim3 grid_dim(1920 / 128, 1080 / 2, 2);   // 15 x 540 x 2 = 16200 blocks
    fused_kernel<<<grid_dim, 256, 0, stream>>>(fullres, wsg, wsw, out);
}

// Round 7
// 36.459 us; speedup vs baseline: 1.1755x; 1.1755x over previous
//
#include <hip/hip_runtime.h>
#include <hip/hip_bf16.h>
#include <math.h>

#define HWV (1080 * 1920)
#define NPIX (2 * HWV)

// ---------------------------------------------------------------------------
// Prep kernel: transpose grid (n,c,z,y,x) -> (n,y,x,z,c) and fold BN.
// ---------------------------------------------------------------------------
__global__ void prep_kernel(const float* __restrict__ grid,
                            const float* __restrict__ w1,
                            const float* __restrict__ b1,
                            const float* __restrict__ gamma,
                            const float* __restrict__ beta,
                            const float* __restrict__ mean,
                            const float* __restrict__ var,
                            const float* __restrict__ w2,
                            const float* __restrict__ b2,
                            float* __restrict__ wsg,   // 49152 floats
                            float* __restrict__ wsw) { // 81 floats
    int i = blockIdx.x * blockDim.x + threadIdx.x;
    if (i < 2 * 12 * 8 * 16 * 16) {
        int c = i % 12;
        int t = i / 12;
        int z = t % 8;  t /= 8;
        int x = t % 16; t /= 16;
        int y = t % 16;
        int n = t / 16;
        wsg[i] = grid[n * 24576 + c * 2048 + z * 256 + y * 16 + x];
    }
    if (i < 16) {
        float inv = gamma[i] / sqrtf(var[i] + 1e-5f);
        wsw[i]      = w1[i * 3 + 0] * inv;
        wsw[16 + i] = w1[i * 3 + 1] * inv;
        wsw[32 + i] = w1[i * 3 + 2] * inv;
        wsw[48 + i] = (b1[i] - mean[i]) * inv + beta[i];
        wsw[64 + i] = w2[i];
    }
    if (i == 0) wsw[80] = b2[0];
}

// ---------------------------------------------------------------------------
// Fused kernel. Block = 512 threads = 1 row x 512 px. Stage the row's
// (<=6 x-cells) y-interpolated grid slab into LDS (576 floats, 1.125/px).
// fullres loads issued BEFORE staging to hide HBM latency under the barrier.
// Per pixel: 12 ds_read_b128 + 48 fma trilinear (all fp32).
// ---------------------------------------------------------------------------
__global__ __launch_bounds__(512, 8) void fused_kernel(
        const float* __restrict__ fullres,
        const float* __restrict__ wsg,
        const float* __restrict__ wsw,
        float* __restrict__ out) {
    __shared__ float sg[6 * 96];   // 6 cells x (8z * 12c), y-lerped

    const int tid = threadIdx.x;
    const int n   = blockIdx.z;
    const int y   = blockIdx.y;
    const int xs  = blockIdx.x * 512;
    const int x   = xs + tid;
    const bool act = (x < 1920);

    // ---- prefetch fullres (clamped addr; latency hides under staging) ----
    const int p  = y * 1920 + min(x, 1919);
    const float* fr = fullres + n * 3 * HWV + p;
    float r = fr[0];
    float g = fr[HWV];
    float b = fr[2 * HWV];

    // ---- stage: <=6 cells x 96 floats, y-lerped (ty row-uniform) ----
    const int a = (int)((float)xs * (15.0f / 1919.0f));
    {
        float gy = (float)y * (15.0f / 1079.0f);
        float y0f = floorf(gy);
        float ty = gy - y0f;
        int y0 = min((int)y0f, 15);
        int y1 = min(y0 + 1, 15);
        const float* gbase = wsg + n * 24576;
        for (int idx = tid; idx < 576; idx += 512) {
            int k = idx / 96;
            int f = idx - k * 96;
            int xc = min(a + k, 15);
            float g0 = gbase[(y0 * 16 + xc) * 96 + f];
            float g1 = gbase[(y1 * 16 + xc) * 96 + f];
            sg[idx] = fmaf(ty, g1 - g0, g0);
        }
    }
    __syncthreads();

    if (!act) return;

    // ---- guide MLP (weights wave-uniform -> s_loads) ----
    float acc = wsw[80];
#pragma unroll
    for (int c = 0; c < 16; ++c) {
        float t = fmaf(wsw[c], r,
                  fmaf(wsw[16 + c], g,
                  fmaf(wsw[32 + c], b, wsw[48 + c])));
        t = fmaxf(t, 0.0f);
        acc = fmaf(wsw[64 + c], t, acc);
    }
    float e = __expf(-acc);
    float guide = __builtin_amdgcn_rcpf(1.0f + e);

    // ---- coords ----
    float gz = guide * 7.0f;
    float z0f = floorf(gz);
    float tz = gz - z0f;
    int z0 = min((int)z0f, 7);
    int z1 = min(z0 + 1, 7);

    float gx = (float)x * (15.0f / 1919.0f);
    float x0f = floorf(gx);
    float tx = gx - x0f;
    int x0 = (int)x0f;
    int k0 = x0 - a;                   // 0..4
    int k1 = min(x0 + 1, 15) - a;      // 0..5

    float wx0 = 1.0f - tx, wx1 = tx;
    float wz0 = 1.0f - tz, wz1 = tz;
    float w00 = wx0 * wz0, w01 = wx0 * wz1;
    float w10 = wx1 * wz0, w11 = wx1 * wz1;

    const float4* s00 = (const float4*)(sg + k0 * 96 + z0 * 12);
    const float4* s01 = (const float4*)(sg + k0 * 96 + z1 * 12);
    const float4* s10 = (const float4*)(sg + k1 * 96 + z0 * 12);
    const float4* s11 = (const float4*)(sg + k1 * 96 + z1 * 12);

    float co[12];
#pragma unroll
    for (int c = 0; c < 12; ++c) co[c] = 0.0f;

#pragma unroll
    for (int q = 0; q < 3; ++q) {
        float4 v00 = s00[q];
        float4 v01 = s01[q];
        float4 v10 = s10[q];
        float4 v11 = s11[q];
        co[q*4+0] = fmaf(w00, v00.x, fmaf(w01, v01.x, fmaf(w10, v10.x, fmaf(w11, v11.x, co[q*4+0]))));
        co[q*4+1] = fmaf(w00, v00.y, fmaf(w01, v01.y, fmaf(w10, v10.y, fmaf(w11, v11.y, co[q*4+1]))));
        co[q*4+2] = fmaf(w00, v00.z, fmaf(w01, v01.z, fmaf(w10, v10.z, fmaf(w11, v11.z, co[q*4+2]))));
        co[q*4+3] = fmaf(w00, v00.w, fmaf(w01, v01.w, fmaf(w10, v10.w, fmaf(w11, v11.w, co[q*4+3]))));
    }

    // ---- apply coeffs ----
    float* op = out + n * 3 * HWV + p;
    op[0]       = fmaf(co[0], r, fmaf(co[1], g, fmaf(co[2],  b, co[3])));
    op[HWV]     = fmaf(co[4], r, fmaf(co[5], g, fmaf(co[6],  b, co[7])));
    op[2 * HWV] = fmaf(co[8], r, fmaf(co[9], g, fmaf(co[10], b, co[11])));
}

extern "C" void kernel_launch(void* const* d_in, const int* in_sizes, int n_in,
                              void* d_out, int out_size, void* d_ws, size_t ws_size,
                              hipStream_t stream) {
    const float* fullres = (const float*)d_in[0];
    const float* grid    = (const float*)d_in[1];
    const float* w1      = (const float*)d_in[2];
    const float* b1      = (const float*)d_in[3];
    const float* gamma   = (const float*)d_in[4];
    const float* beta    = (const float*)d_in[5];
    const float* mean    = (const float*)d_in[6];
    const float* var     = (const float*)d_in[7];
    const float* w2      = (const float*)d_in[8];
    const float* b2      = (const float*)d_in[9];
    float* out = (float*)d_out;

    float* wsg = (float*)d_ws;
    float* wsw = wsg + 49152;

    prep_kernel<<<192, 256, 0, stream>>>(grid, w1, b1, gamma, beta, mean, var,
                                         w2, b2, wsg, wsw);

    dim3 grid_dim(4, 1080, 2);   // 4 x-segments x 1080 rows x 2 images
    fused_kernel<<<grid_dim, 512, 0, stream>>>(fullres, wsg, wsw, out);
}

// Round 8
// 33.637 us; speedup vs baseline: 1.2741x; 1.0839x over previous
//
#include <hip/hip_runtime.h>
#include <hip/hip_bf16.h>
#include <math.h>

#define HWV (1080 * 1920)
#define NPIX (2 * HWV)

typedef _Float16 half2 __attribute__((ext_vector_type(2)));
typedef __fp16   pk2   __attribute__((ext_vector_type(2)));
union U32H2 { unsigned u; half2 h; pk2 p; };

// ---------------------------------------------------------------------------
// Prep kernel: transpose grid (n,c,z,y,x) -> (n,y,x,z,c), fold BN, and pack
// first-layer weights as half2 pairs (hidden units 2i,2i+1) for v_pk_fma_f16.
// wsw layout: [0..15]=wr [16..31]=wg [32..47]=wb [48..63]=bias [64..79]=w2
//             [80]=b2   [84..115] (as u32) = packed {wr,wg,wb,bias} per pair
// ---------------------------------------------------------------------------
__global__ void prep_kernel(const float* __restrict__ grid,
                            const float* __restrict__ w1,
                            const float* __restrict__ b1,
                            const float* __restrict__ gamma,
                            const float* __restrict__ beta,
                            const float* __restrict__ mean,
                            const float* __restrict__ var,
                            const float* __restrict__ w2,
                            const float* __restrict__ b2,
                            float* __restrict__ wsg,   // 49152 floats
                            float* __restrict__ wsw) { // 116 floats
    int i = blockIdx.x * blockDim.x + threadIdx.x;
    if (i < 2 * 12 * 8 * 16 * 16) {
        int c = i % 12;
        int t = i / 12;
        int z = t % 8;  t /= 8;
        int x = t % 16; t /= 16;
        int y = t % 16;
        int n = t / 16;
        wsg[i] = grid[n * 24576 + c * 2048 + z * 256 + y * 16 + x];
    }
    if (i < 16) {
        float inv = gamma[i] / sqrtf(var[i] + 1e-5f);
        wsw[i]      = w1[i * 3 + 0] * inv;
        wsw[16 + i] = w1[i * 3 + 1] * inv;
        wsw[32 + i] = w1[i * 3 + 2] * inv;
        wsw[48 + i] = (b1[i] - mean[i]) * inv + beta[i];
        wsw[64 + i] = w2[i];
    }
    if (i == 0) wsw[80] = b2[0];
    if (i < 8) {
        int c0 = 2 * i, c1 = 2 * i + 1;
        float inv0 = gamma[c0] / sqrtf(var[c0] + 1e-5f);
        float inv1 = gamma[c1] / sqrtf(var[c1] + 1e-5f);
        unsigned* wp = (unsigned*)(wsw + 84);
        U32H2 t;
        t.p = __builtin_amdgcn_cvt_pkrtz(w1[c0*3+0] * inv0, w1[c1*3+0] * inv1);
        wp[i * 4 + 0] = t.u;
        t.p = __builtin_amdgcn_cvt_pkrtz(w1[c0*3+1] * inv0, w1[c1*3+1] * inv1);
        wp[i * 4 + 1] = t.u;
        t.p = __builtin_amdgcn_cvt_pkrtz(w1[c0*3+2] * inv0, w1[c1*3+2] * inv1);
        wp[i * 4 + 2] = t.u;
        t.p = __builtin_amdgcn_cvt_pkrtz((b1[c0] - mean[c0]) * inv0 + beta[c0],
                                         (b1[c1] - mean[c1]) * inv1 + beta[c1]);
        wp[i * 4 + 3] = t.u;
    }
}

// ---------------------------------------------------------------------------
// Fused kernel. Block = 512 threads = 1 row x 512 px. Row slab y-lerped into
// LDS. Guide MLP: packed-f16 first layer (v_pk_fma_f16), f32 accumulate.
// ---------------------------------------------------------------------------
__global__ __launch_bounds__(512, 8) void fused_kernel(
        const float* __restrict__ fullres,
        const float* __restrict__ wsg,
        const float* __restrict__ wsw,
        float* __restrict__ out) {
    __shared__ float sg[6 * 96];   // 6 cells x (8z * 12c), y-lerped

    const int tid = threadIdx.x;
    const int n   = blockIdx.z;
    const int y   = blockIdx.y;
    const int xs  = blockIdx.x * 512;
    const int x   = xs + tid;
    const bool act = (x < 1920);

    // ---- prefetch fullres (clamped addr; latency hides under staging) ----
    const int p  = y * 1920 + min(x, 1919);
    const float* fr = fullres + n * 3 * HWV + p;
    float r = fr[0];
    float g = fr[HWV];
    float b = fr[2 * HWV];

    // ---- stage: <=6 cells x 96 floats, y-lerped (ty row-uniform) ----
    const int a = (int)((float)xs * (15.0f / 1919.0f));
    {
        float gy = (float)y * (15.0f / 1079.0f);
        float y0f = floorf(gy);
        float ty = gy - y0f;
        int y0 = min((int)y0f, 15);
        int y1 = min(y0 + 1, 15);
        const float* gbase = wsg + n * 24576;
        for (int idx = tid; idx < 576; idx += 512) {
            int k = idx / 96;
            int f = idx - k * 96;
            int xc = min(a + k, 15);
            float g0 = gbase[(y0 * 16 + xc) * 96 + f];
            float g1 = gbase[(y1 * 16 + xc) * 96 + f];
            sg[idx] = fmaf(ty, g1 - g0, g0);
        }
    }
    __syncthreads();

    if (!act) return;

    // ---- guide MLP: packed f16 hidden layer, f32 accumulate ----
    U32H2 rr, gg, bb;
    rr.p = __builtin_amdgcn_cvt_pkrtz(r, r);
    gg.p = __builtin_amdgcn_cvt_pkrtz(g, g);
    bb.p = __builtin_amdgcn_cvt_pkrtz(b, b);
    const unsigned* wp = (const unsigned*)(wsw + 84);
    const half2 zero = {(_Float16)0.0f, (_Float16)0.0f};
    float acc = wsw[80];
#pragma unroll
    for (int c2 = 0; c2 < 8; ++c2) {
        U32H2 wr, wg, wb, wbs;
        wr.u  = wp[c2 * 4 + 0];
        wg.u  = wp[c2 * 4 + 1];
        wb.u  = wp[c2 * 4 + 2];
        wbs.u = wp[c2 * 4 + 3];
        half2 h = wr.h * rr.h + (wg.h * gg.h + (wb.h * bb.h + wbs.h));
        h = __builtin_elementwise_max(h, zero);
        acc = fmaf((float)h.x, wsw[64 + 2 * c2],     acc);
        acc = fmaf((float)h.y, wsw[64 + 2 * c2 + 1], acc);
    }
    float e = __expf(-acc);
    float guide = __builtin_amdgcn_rcpf(1.0f + e);

    // ---- coords ----
    float gz = guide * 7.0f;
    float z0f = floorf(gz);
    float tz = gz - z0f;
    int z0 = min((int)z0f, 7);
    int z1 = min(z0 + 1, 7);

    float gx = (float)x * (15.0f / 1919.0f);
    float x0f = floorf(gx);
    float tx = gx - x0f;
    int x0 = (int)x0f;
    int k0 = x0 - a;                   // 0..4
    int k1 = min(x0 + 1, 15) - a;      // 0..5

    float wx0 = 1.0f - tx, wx1 = tx;
    float wz0 = 1.0f - tz, wz1 = tz;
    float w00 = wx0 * wz0, w01 = wx0 * wz1;
    float w10 = wx1 * wz0, w11 = wx1 * wz1;

    const float4* s00 = (const float4*)(sg + k0 * 96 + z0 * 12);
    const float4* s01 = (const float4*)(sg + k0 * 96 + z1 * 12);
    const float4* s10 = (const float4*)(sg + k1 * 96 + z0 * 12);
    const float4* s11 = (const float4*)(sg + k1 * 96 + z1 * 12);

    float co[12];
#pragma unroll
    for (int c = 0; c < 12; ++c) co[c] = 0.0f;

#pragma unroll
    for (int q = 0; q < 3; ++q) {
        float4 v00 = s00[q];
        float4 v01 = s01[q];
        float4 v10 = s10[q];
        float4 v11 = s11[q];
        co[q*4+0] = fmaf(w00, v00.x, fmaf(w01, v01.x, fmaf(w10, v10.x, fmaf(w11, v11.x, co[q*4+0]))));
        co[q*4+1] = fmaf(w00, v00.y, fmaf(w01, v01.y, fmaf(w10, v10.y, fmaf(w11, v11.y, co[q*4+1]))));
        co[q*4+2] = fmaf(w00, v00.z, fmaf(w01, v01.z, fmaf(w10, v10.z, fmaf(w11, v11.z, co[q*4+2]))));
        co[q*4+3] = fmaf(w00, v00.w, fmaf(w01, v01.w, fmaf(w10, v10.w, fmaf(w11, v11.w, co[q*4+3]))));
    }

    // ---- apply coeffs ----
    float* op = out + n * 3 * HWV + p;
    op[0]       = fmaf(co[0], r, fmaf(co[1], g, fmaf(co[2],  b, co[3])));
    op[HWV]     = fmaf(co[4], r, fmaf(co[5], g, fmaf(co[6],  b, co[7])));
    op[2 * HWV] = fmaf(co[8], r, fmaf(co[9], g, fmaf(co[10], b, co[11])));
}

extern "C" void kernel_launch(void* const* d_in, const int* in_sizes, int n_in,
                              void* d_out, int out_size, void* d_ws, size_t ws_size,
                              hipStream_t stream) {
    const float* fullres = (const float*)d_in[0];
    const float* grid    = (const float*)d_in[1];
    const float* w1      = (const float*)d_in[2];
    const float* b1      = (const float*)d_in[3];
    const float* gamma   = (const float*)d_in[4];
    const float* beta    = (const float*)d_in[5];
    const float* mean    = (const float*)d_in[6];
    const float* var     = (const float*)d_in[7];
    const float* w2      = (const float*)d_in[8];
    const float* b2      = (const float*)d_in[9];
    float* out = (float*)d_out;

    float* wsg = (float*)d_ws;
    float* wsw = wsg + 49152;

    prep_kernel<<<192, 256, 0, stream>>>(grid, w1, b1, gamma, beta, mean, var,
                                         w2, b2, wsg, wsw);

    dim3 grid_dim(4, 1080, 2);   // 4 x-segments x 1080 rows x 2 images
    fused_kernel<<<grid_dim, 512, 0, stream>>>(fullres, wsg, wsw, out);
}

// Round 9
// 33.375 us; speedup vs baseline: 1.2841x; 1.0078x over previous
//
#include <hip/hip_runtime.h>
#include <hip/hip_bf16.h>
#include <math.h>

#define HWV (1080 * 1920)
#define NPIX (2 * HWV)

typedef _Float16 half2 __attribute__((ext_vector_type(2)));
typedef __fp16   pk2   __attribute__((ext_vector_type(2)));
union U32H2 { unsigned u; half2 h; pk2 p; };

// ---------------------------------------------------------------------------
// Prep kernel: transpose grid (n,c,z,y,x) -> (n,y,x,z,c), fold BN, and pack
// first-layer weights as half2 pairs (hidden units 2i,2i+1) for v_pk_fma_f16.
// wsw layout: [0..15]=wr [16..31]=wg [32..47]=wb [48..63]=bias [64..79]=w2
//             [80]=b2   [84..115] (as u32) = packed {wr,wg,wb,bias} per pair
// ---------------------------------------------------------------------------
__global__ void prep_kernel(const float* __restrict__ grid,
                            const float* __restrict__ w1,
                            const float* __restrict__ b1,
                            const float* __restrict__ gamma,
                            const float* __restrict__ beta,
                            const float* __restrict__ mean,
                            const float* __restrict__ var,
                            const float* __restrict__ w2,
                            const float* __restrict__ b2,
                            float* __restrict__ wsg,   // 49152 floats
                            float* __restrict__ wsw) { // 116 floats
    int i = blockIdx.x * blockDim.x + threadIdx.x;
    if (i < 2 * 12 * 8 * 16 * 16) {
        int c = i % 12;
        int t = i / 12;
        int z = t % 8;  t /= 8;
        int x = t % 16; t /= 16;
        int y = t % 16;
        int n = t / 16;
        wsg[i] = grid[n * 24576 + c * 2048 + z * 256 + y * 16 + x];
    }
    if (i < 16) {
        float inv = gamma[i] / sqrtf(var[i] + 1e-5f);
        wsw[i]      = w1[i * 3 + 0] * inv;
        wsw[16 + i] = w1[i * 3 + 1] * inv;
        wsw[32 + i] = w1[i * 3 + 2] * inv;
        wsw[48 + i] = (b1[i] - mean[i]) * inv + beta[i];
        wsw[64 + i] = w2[i];
    }
    if (i == 0) wsw[80] = b2[0];
    if (i < 8) {
        int c0 = 2 * i, c1 = 2 * i + 1;
        float inv0 = gamma[c0] / sqrtf(var[c0] + 1e-5f);
        float inv1 = gamma[c1] / sqrtf(var[c1] + 1e-5f);
        unsigned* wp = (unsigned*)(wsw + 84);
        U32H2 t;
        t.p = __builtin_amdgcn_cvt_pkrtz(w1[c0*3+0] * inv0, w1[c1*3+0] * inv1);
        wp[i * 4 + 0] = t.u;
        t.p = __builtin_amdgcn_cvt_pkrtz(w1[c0*3+1] * inv0, w1[c1*3+1] * inv1);
        wp[i * 4 + 1] = t.u;
        t.p = __builtin_amdgcn_cvt_pkrtz(w1[c0*3+2] * inv0, w1[c1*3+2] * inv1);
        wp[i * 4 + 2] = t.u;
        t.p = __builtin_amdgcn_cvt_pkrtz((b1[c0] - mean[c0]) * inv0 + beta[c0],
                                         (b1[c1] - mean[c1]) * inv1 + beta[c1]);
        wp[i * 4 + 3] = t.u;
    }
}

// ---------------------------------------------------------------------------
// Fused kernel. Block = 512 threads = 1 row x 512 px. Row slab y-lerped into
// LDS as channel-pair half2, with z=7 duplicated into slot 8 so z1=z0+1
// needs no clamp. Per pixel: 4 ds_read_b128 + 4 ds_read_b64, 24 v_pk_fma_f16
// trilinear, fma_mix apply. Guide MLP in packed f16 (round 8).
// ---------------------------------------------------------------------------
__global__ __launch_bounds__(512, 8) void fused_kernel(
        const float* __restrict__ fullres,
        const float* __restrict__ wsg,
        const float* __restrict__ wsw,
        float* __restrict__ out) {
    __shared__ unsigned slo[6][9][4];   // [cell][z][ch-pairs 0..3]
    __shared__ unsigned shi[6][9][2];   // [cell][z][ch-pairs 4..5]

    const int tid = threadIdx.x;
    const int n   = blockIdx.z;
    const int y   = blockIdx.y;
    const int xs  = blockIdx.x * 512;
    const int x   = xs + tid;
    const bool act = (x < 1920);

    // ---- prefetch fullres (clamped addr; latency hides under staging) ----
    const int p  = y * 1920 + min(x, 1919);
    const float* fr = fullres + n * 3 * HWV + p;
    float r = fr[0];
    float g = fr[HWV];
    float b = fr[2 * HWV];

    // ---- stage: 6 cells x 9 z x 6 ch-pairs, y-lerped, f16-packed ----
    const int a = (int)((float)xs * (15.0f / 1919.0f));
    {
        float gy = (float)y * (15.0f / 1079.0f);
        float y0f = floorf(gy);
        float ty = gy - y0f;
        int y0 = min((int)y0f, 15);
        int y1 = min(y0 + 1, 15);
        const float* gbase = wsg + n * 24576;
        if (tid < 324) {
            int k = tid / 54;
            int rem = tid - k * 54;
            int z = rem / 6;            // 0..8
            int j = rem - z * 6;        // ch-pair
            int zz = min(z, 7);
            int xc = min(a + k, 15);
            const float2 v0 = *(const float2*)(gbase + ((y0 * 16 + xc) * 8 + zz) * 12 + 2 * j);
            const float2 v1 = *(const float2*)(gbase + ((y1 * 16 + xc) * 8 + zz) * 12 + 2 * j);
            float e0 = fmaf(ty, v1.x - v0.x, v0.x);
            float e1 = fmaf(ty, v1.y - v0.y, v0.y);
            U32H2 t;
            t.p = __builtin_amdgcn_cvt_pkrtz(e0, e1);
            if (j < 4) slo[k][z][j] = t.u;
            else       shi[k][z][j - 4] = t.u;
        }
    }
    __syncthreads();

    if (!act) return;

    // ---- guide MLP: packed f16 hidden layer, f32 accumulate ----
    U32H2 rr, gg, bb;
    rr.p = __builtin_amdgcn_cvt_pkrtz(r, r);
    gg.p = __builtin_amdgcn_cvt_pkrtz(g, g);
    bb.p = __builtin_amdgcn_cvt_pkrtz(b, b);
    const unsigned* wp = (const unsigned*)(wsw + 84);
    const half2 zero = {(_Float16)0.0f, (_Float16)0.0f};
    float acc = wsw[80];
#pragma unroll
    for (int c2 = 0; c2 < 8; ++c2) {
        U32H2 wr, wg, wb, wbs;
        wr.u  = wp[c2 * 4 + 0];
        wg.u  = wp[c2 * 4 + 1];
        wb.u  = wp[c2 * 4 + 2];
        wbs.u = wp[c2 * 4 + 3];
        half2 h = wr.h * rr.h + (wg.h * gg.h + (wb.h * bb.h + wbs.h));
        h = __builtin_elementwise_max(h, zero);
        acc = fmaf((float)h.x, wsw[64 + 2 * c2],     acc);
        acc = fmaf((float)h.y, wsw[64 + 2 * c2 + 1], acc);
    }
    float e = __expf(-acc);
    float guide = __builtin_amdgcn_rcpf(1.0f + e);

    // ---- coords ----
    float gz = guide * 7.0f;
    float z0f = floorf(gz);
    float tz = gz - z0f;
    int z0 = min((int)z0f, 7);
    int z1 = z0 + 1;                   // slot 8 duplicates z=7

    float gx = (float)x * (15.0f / 1919.0f);
    float x0f = floorf(gx);
    float tx = gx - x0f;
    int x0 = (int)x0f;
    int k0 = x0 - a;                   // 0..4
    int k1 = min(x0 + 1, 15) - a;      // 0..5

    float wx0 = 1.0f - tx, wx1 = tx;
    float wz0 = 1.0f - tz, wz1 = tz;

    U32H2 w00h, w01h, w10h, w11h;
    w00h.p = __builtin_amdgcn_cvt_pkrtz(wx0 * wz0, wx0 * wz0);
    w01h.p = __builtin_amdgcn_cvt_pkrtz(wx0 * wz1, wx0 * wz1);
    w10h.p = __builtin_amdgcn_cvt_pkrtz(wx1 * wz0, wx1 * wz0);
    w11h.p = __builtin_amdgcn_cvt_pkrtz(wx1 * wz1, wx1 * wz1);

    const uint4 A0 = *(const uint4*)&slo[k0][z0][0];
    const uint4 A1 = *(const uint4*)&slo[k0][z1][0];
    const uint4 B0 = *(const uint4*)&slo[k1][z0][0];
    const uint4 B1 = *(const uint4*)&slo[k1][z1][0];
    const uint2 C0 = *(const uint2*)&shi[k0][z0][0];
    const uint2 C1 = *(const uint2*)&shi[k0][z1][0];
    const uint2 D0 = *(const uint2*)&shi[k1][z0][0];
    const uint2 D1 = *(const uint2*)&shi[k1][z1][0];

    unsigned a0j[6] = {A0.x, A0.y, A0.z, A0.w, C0.x, C0.y};
    unsigned a1j[6] = {A1.x, A1.y, A1.z, A1.w, C1.x, C1.y};
    unsigned b0j[6] = {B0.x, B0.y, B0.z, B0.w, D0.x, D0.y};
    unsigned b1j[6] = {B1.x, B1.y, B1.z, B1.w, D1.x, D1.y};

    half2 hc[6];
#pragma unroll
    for (int j = 0; j < 6; ++j) {
        U32H2 ua0, ua1, ub0, ub1;
        ua0.u = a0j[j]; ua1.u = a1j[j]; ub0.u = b0j[j]; ub1.u = b1j[j];
        half2 h = w00h.h * ua0.h + (w01h.h * ua1.h);
        h = w10h.h * ub0.h + h;
        h = w11h.h * ub1.h + h;
        hc[j] = h;
    }

    // ---- apply coeffs (f16 halves consumed via fma_mix) ----
    float* op = out + n * 3 * HWV + p;
    op[0]       = fmaf((float)hc[0].x, r, fmaf((float)hc[0].y, g,
                  fmaf((float)hc[1].x, b, (float)hc[1].y)));
    op[HWV]     = fmaf((float)hc[2].x, r, fmaf((float)hc[2].y, g,
                  fmaf((float)hc[3].x, b, (float)hc[3].y)));
    op[2 * HWV] = fmaf((float)hc[4].x, r, fmaf((float)hc[4].y, g,
                  fmaf((float)hc[5].x, b, (float)hc[5].y)));
}

extern "C" void kernel_launch(void* const* d_in, const int* in_sizes, int n_in,
                              void* d_out, int out_size, void* d_ws, size_t ws_size,
                              hipStream_t stream) {
    const float* fullres = (const float*)d_in[0];
    const float* grid    = (const float*)d_in[1];
    const float* w1      = (const float*)d_in[2];
    const float* b1      = (const float*)d_in[3];
    const float* gamma   = (const float*)d_in[4];
    const float* beta    = (const float*)d_in[5];
    const float* mean    = (const float*)d_in[6];
    const float* var     = (const float*)d_in[7];
    const float* w2      = (const float*)d_in[8];
    const float* b2      = (const float*)d_in[9];
    float* out = (float*)d_out;

    float* wsg = (float*)d_ws;
    float* wsw = wsg + 49152;

    prep_kernel<<<192, 256, 0, stream>>>(grid, w1, b1, gamma, beta, mean, var,
                                         w2, b2, wsg, wsw);

    dim3 grid_dim(4, 1080, 2);   // 4 x-segments x 1080 rows x 2 images
    fused_kernel<<<grid_dim, 512, 0, stream>>>(fullres, wsg, wsw, out);
}

// Round 10
// 32.253 us; speedup vs baseline: 1.3288x; 1.0348x over previous
//
#include <hip/hip_runtime.h>
#include <hip/hip_bf16.h>
#include <math.h>

#define HWV (1080 * 1920)

typedef _Float16 half2 __attribute__((ext_vector_type(2)));
typedef __fp16   pk2   __attribute__((ext_vector_type(2)));
union U32H2 { unsigned u; half2 h; pk2 p; };

// ---------------------------------------------------------------------------
// Weight prep (1 block): fold BN, pack f16 weights duplicated per lane-pair
// so one packed register serves 2 pixels. Layout in wsw:
//   [64..79] = w2 (f32)   [80] = b2
//   u32 wp = (unsigned*)(wsw+84): wp[4c+{0,1,2,3}] = {wr,wr},{wg,wg},{wb,wb},{bs,bs}
// ---------------------------------------------------------------------------
__global__ void prep_w(const float* __restrict__ w1, const float* __restrict__ b1,
                       const float* __restrict__ gamma, const float* __restrict__ beta,
                       const float* __restrict__ mean, const float* __restrict__ var,
                       const float* __restrict__ w2, const float* __restrict__ b2,
                       float* __restrict__ wsw) {
    int i = threadIdx.x;
    if (i < 16) {
        float inv = gamma[i] / sqrtf(var[i] + 1e-5f);
        float wr = w1[i*3+0] * inv, wg = w1[i*3+1] * inv, wb = w1[i*3+2] * inv;
        float bs = (b1[i] - mean[i]) * inv + beta[i];
        wsw[64 + i] = w2[i];
        unsigned* wp = (unsigned*)(wsw + 84);
        U32H2 t;
        t.p = __builtin_amdgcn_cvt_pkrtz(wr, wr); wp[i*4+0] = t.u;
        t.p = __builtin_amdgcn_cvt_pkrtz(wg, wg); wp[i*4+1] = t.u;
        t.p = __builtin_amdgcn_cvt_pkrtz(wb, wb); wp[i*4+2] = t.u;
        t.p = __builtin_amdgcn_cvt_pkrtz(bs, bs); wp[i*4+3] = t.u;
    }
    if (i == 0) wsw[80] = b2[0];
}

// ---------------------------------------------------------------------------
// Fused kernel. Block = 512 threads, each 2 adjacent px (1024 px of one row).
// Stage directly from the ORIGINAL grid layout (L2-hot), y-lerped, f16-packed
// channel pairs, z=7 duplicated into slot 8. Two independent per-pixel chains
// per thread for ILP; float2 global I/O.
// ---------------------------------------------------------------------------
__global__ __launch_bounds__(512, 8) void fused_kernel(
        const float* __restrict__ fullres,
        const float* __restrict__ grid,
        const float* __restrict__ wsw,
        float* __restrict__ out) {
    __shared__ unsigned slo[9][9][4];   // [cell][z][ch-pairs 0..3]
    __shared__ unsigned shi[9][9][2];   // [cell][z][ch-pairs 4..5]

    const int tid = threadIdx.x;
    const int n   = blockIdx.z;
    const int y   = blockIdx.y;
    const int xs  = blockIdx.x * 1024;
    const int x   = xs + 2 * tid;
    const bool act = (x < 1920);

    // ---- prefetch fullres (clamped addr; latency hides under staging) ----
    const int p = y * 1920 + min(x, 1918);
    const float* fr = fullres + n * 3 * HWV + p;
    float2 R = *(const float2*)(fr);
    float2 G = *(const float2*)(fr + HWV);
    float2 B = *(const float2*)(fr + 2 * HWV);

    // ---- stage: 9 cells x 9 z x 6 ch-pairs from original layout ----
    const int a = (int)((float)xs * (15.0f / 1919.0f));
    {
        float gy = (float)y * (15.0f / 1079.0f);
        float y0f = floorf(gy);
        float ty = gy - y0f;
        int y0 = min((int)y0f, 15);
        int y1 = min(y0 + 1, 15);
        const int dy = (y1 - y0) * 16;
        const float* gb = grid + n * 24576 + y0 * 16;
        if (tid < 486) {
            int j   = tid / 81;           // ch-pair 0..5
            int rem = tid - j * 81;
            int z   = rem / 9;            // 0..8
            int k   = rem - z * 9;        // cell 0..8
            int zz  = min(z, 7);
            int xc  = min(a + k, 15);
            const float* q0 = gb + (2 * j) * 2048 + zz * 256 + xc;
            const float* q1 = q0 + 2048;
            float v00 = q0[0], v01 = q0[dy];
            float v10 = q1[0], v11 = q1[dy];
            float e0 = fmaf(ty, v01 - v00, v00);
            float e1 = fmaf(ty, v11 - v10, v10);
            U32H2 t;
            t.p = __builtin_amdgcn_cvt_pkrtz(e0, e1);
            if (j < 4) slo[k][z][j] = t.u;
            else       shi[k][z][j - 4] = t.u;
        }
    }
    __syncthreads();

    if (!act) return;

    // ---- guide MLP: both pixels share packed weight regs ----
    U32H2 rr, gg, bb;
    rr.p = __builtin_amdgcn_cvt_pkrtz(R.x, R.y);
    gg.p = __builtin_amdgcn_cvt_pkrtz(G.x, G.y);
    bb.p = __builtin_amdgcn_cvt_pkrtz(B.x, B.y);
    const unsigned* wp = (const unsigned*)(wsw + 84);
    const half2 zero = {(_Float16)0.0f, (_Float16)0.0f};
    float b2s = wsw[80];
    float acc0 = b2s, acc1 = b2s;
#pragma unroll
    for (int c = 0; c < 16; ++c) {
        U32H2 wr, wg, wb, bs;
        wr.u = wp[4*c+0]; wg.u = wp[4*c+1]; wb.u = wp[4*c+2]; bs.u = wp[4*c+3];
        half2 h = wr.h * rr.h + (wg.h * gg.h + (wb.h * bb.h + bs.h));
        h = __builtin_elementwise_max(h, zero);
        float w2c = wsw[64 + c];
        acc0 = fmaf((float)h.x, w2c, acc0);
        acc1 = fmaf((float)h.y, w2c, acc1);
    }

    float accv[2] = {acc0, acc1};
    float rv[2] = {R.x, R.y}, gv[2] = {G.x, G.y}, bv[2] = {B.x, B.y};
    float outr[2], outg[2], outb[2];

#pragma unroll
    for (int q = 0; q < 2; ++q) {
        float e = __expf(-accv[q]);
        float guide = __builtin_amdgcn_rcpf(1.0f + e);
        float gz = guide * 7.0f;
        float z0f = floorf(gz);
        float tz = gz - z0f;
        int z0 = min((int)z0f, 7);
        int z1 = z0 + 1;               // slot 8 duplicates z=7

        float gx = (float)(x + q) * (15.0f / 1919.0f);
        float x0f = floorf(gx);
        float tx = gx - x0f;
        int x0 = (int)x0f;
        int k0 = x0 - a;               // 0..8
        int k1 = min(x0 + 1, 15) - a;  // 0..8

        float wx0 = 1.0f - tx, wx1 = tx;
        float wz0 = 1.0f - tz, wz1 = tz;

        U32H2 w00h, w01h, w10h, w11h;
        w00h.p = __builtin_amdgcn_cvt_pkrtz(wx0 * wz0, wx0 * wz0);
        w01h.p = __builtin_amdgcn_cvt_pkrtz(wx0 * wz1, wx0 * wz1);
        w10h.p = __builtin_amdgcn_cvt_pkrtz(wx1 * wz0, wx1 * wz0);
        w11h.p = __builtin_amdgcn_cvt_pkrtz(wx1 * wz1, wx1 * wz1);

        const uint4 A0 = *(const uint4*)&slo[k0][z0][0];
        const uint4 A1 = *(const uint4*)&slo[k0][z1][0];
        const uint4 B0 = *(const uint4*)&slo[k1][z0][0];
        const uint4 B1 = *(const uint4*)&slo[k1][z1][0];
        const uint2 C0 = *(const uint2*)&shi[k0][z0][0];
        const uint2 C1 = *(const uint2*)&shi[k0][z1][0];
        const uint2 D0 = *(const uint2*)&shi[k1][z0][0];
        const uint2 D1 = *(const uint2*)&shi[k1][z1][0];

        unsigned a0j[6] = {A0.x, A0.y, A0.z, A0.w, C0.x, C0.y};
        unsigned a1j[6] = {A1.x, A1.y, A1.z, A1.w, C1.x, C1.y};
        unsigned b0j[6] = {B0.x, B0.y, B0.z, B0.w, D0.x, D0.y};
        unsigned b1j[6] = {B1.x, B1.y, B1.z, B1.w, D1.x, D1.y};

        half2 hc[6];
#pragma unroll
        for (int j = 0; j < 6; ++j) {
            U32H2 ua0, ua1, ub0, ub1;
            ua0.u = a0j[j]; ua1.u = a1j[j]; ub0.u = b0j[j]; ub1.u = b1j[j];
            half2 h = w00h.h * ua0.h + (w01h.h * ua1.h);
            h = w10h.h * ub0.h + h;
            h = w11h.h * ub1.h + h;
            hc[j] = h;
        }

        outr[q] = fmaf((float)hc[0].x, rv[q], fmaf((float)hc[0].y, gv[q],
                  fmaf((float)hc[1].x, bv[q], (float)hc[1].y)));
        outg[q] = fmaf((float)hc[2].x, rv[q], fmaf((float)hc[2].y, gv[q],
                  fmaf((float)hc[3].x, bv[q], (float)hc[3].y)));
        outb[q] = fmaf((float)hc[4].x, rv[q], fmaf((float)hc[4].y, gv[q],
                  fmaf((float)hc[5].x, bv[q], (float)hc[5].y)));
    }

    float* op = out + n * 3 * HWV + p;
    *(float2*)(op)           = make_float2(outr[0], outr[1]);
    *(float2*)(op + HWV)     = make_float2(outg[0], outg[1]);
    *(float2*)(op + 2 * HWV) = make_float2(outb[0], outb[1]);
}

extern "C" void kernel_launch(void* const* d_in, const int* in_sizes, int n_in,
                              void* d_out, int out_size, void* d_ws, size_t ws_size,
                              hipStream_t stream) {
    const float* fullres = (const float*)d_in[0];
    const float* grid    = (const float*)d_in[1];
    const float* w1      = (const float*)d_in[2];
    const float* b1      = (const float*)d_in[3];
    const float* gamma   = (const float*)d_in[4];
    const float* beta    = (const float*)d_in[5];
    const float* mean    = (const float*)d_in[6];
    const float* var     = (const float*)d_in[7];
    const float* w2      = (const float*)d_in[8];
    const float* b2      = (const float*)d_in[9];
    float* out = (float*)d_out;

    float* wsw = (float*)d_ws;   // 148 floats used

    prep_w<<<1, 64, 0, stream>>>(w1, b1, gamma, beta, mean, var, w2, b2, wsw);

    dim3 grid_dim(2, 1080, 2);   // 2 x-segments x 1080 rows x 2 images
    fused_kernel<<<grid_dim, 512, 0, stream>>>(fullres, grid, wsw, out);
}